// Round 11
// baseline (104.344 us; speedup 1.0000x reference)
//
#include <hip/hip_runtime.h>

// Cost volume: out[b,d,h,w] = (1/C) * sum_c L[c,w] * R[c,w-d], zero for w<d.
// B=8, C=128, H=96, W=320, D=48, fp32 in/out.
//
// Round 11: r10 (MFMA banded-Gram, verified correct) was register-starved:
// VGPR=96 -> compiler serialized the 88 scalar loads per kc behind each mfma,
// nothing >8% busy. Fix: __launch_bounds__(256,1) for VGPR headroom + explicit
// register double-buffer of the frag sets, K fully unrolled:
//   load(kc0)->S0; load(kc1)->S1; mfma(S0); load(kc2)->S0; mfma(S1);
//   load(kc3)->S1; mfma(S0); mfma(S1)
// ~88 independent loads in flight; no LDS, no barriers (r8 lesson).
// Mapping (verified r10, absmax 2e-3): A-frag m=w, B-frag n=w', k=c with the
// same lane->k map on both sides (permutation cancels); C/D: col=lane&15=w',
// row=(lane>>4)*4+reg=w [m89]. Band covered by 7 sliding B-frags per 64-w wave.

typedef _Float16 half8 __attribute__((ext_vector_type(8)));
typedef float f32x4 __attribute__((ext_vector_type(4)));

constexpr int Cn = 128, Hn = 96, Wn = 320, Dn = 48;
constexpr long long PL = (long long)Hn * Wn;   // 30720

__device__ __forceinline__ half8 load_frag(const float* __restrict__ P, long long o) {
  half8 f;
#pragma unroll
  for (int j = 0; j < 8; ++j) f[j] = (_Float16)P[o + (long long)j * PL];
  return f;
}

__device__ __forceinline__
void load_set(const float* __restrict__ L, const float* __restrict__ R,
              long long cb, int wbase, int lo, half8 A[4], half8 B[7]) {
#pragma unroll
  for (int i = 0; i < 7; ++i) {
    long long o = cb + (wbase - 48 + 16 * i + lo);
    o = o < 0 ? 0 : o;                 // clamp: garbage masked at store
    B[i] = load_frag(R, o);
  }
#pragma unroll
  for (int i = 0; i < 4; ++i)
    A[i] = load_frag(L, cb + (wbase + 16 * i + lo));
}

__device__ __forceinline__
void mfma_set(const half8 A[4], const half8 B[7], f32x4 acc[4][4]) {
#pragma unroll
  for (int wt = 0; wt < 4; ++wt)
#pragma unroll
    for (int bt = 0; bt < 4; ++bt)
      acc[wt][bt] =
          __builtin_amdgcn_mfma_f32_16x16x32_f16(A[wt], B[wt + bt], acc[wt][bt], 0, 0, 0);
}

__global__ __launch_bounds__(256, 1)
void costvol_kernel(const float* __restrict__ L, const float* __restrict__ R,
                    float* __restrict__ out) {
  const int bid = blockIdx.x;
  const int swz = (bid & 7) * 120 + (bid >> 3);   // bijective XCD-contiguous map
  const int wid = threadIdx.x >> 6, lane = threadIdx.x & 63;
  const int gw = swz * 4 + wid;                   // 3840 = 768 (b,h) x 5 w-slots
  const int bh = gw / 5, ws = gw - bh * 5;
  const int b = bh / Hn, h = bh - b * Hn;
  const int wbase = ws * 64;
  const int lo = lane & 15, hi = lane >> 4;

  const long long base = (long long)b * Cn * PL + (long long)h * Wn;
  const long long kstep = (long long)32 * PL;
  const long long cb0 = base + (long long)(hi * 8) * PL;

  f32x4 acc[4][4];
#pragma unroll
  for (int i = 0; i < 4; ++i)
#pragma unroll
    for (int j = 0; j < 4; ++j)
      acc[i][j] = f32x4{0.f, 0.f, 0.f, 0.f};

  half8 A0[4], B0[7], A1[4], B1[7];

  // Register-pipelined, K fully unrolled (4 steps of k=32).
  load_set(L, R, cb0 + 0 * kstep, wbase, lo, A0, B0);
  load_set(L, R, cb0 + 1 * kstep, wbase, lo, A1, B1);
  mfma_set(A0, B0, acc);
  load_set(L, R, cb0 + 2 * kstep, wbase, lo, A0, B0);
  mfma_set(A1, B1, acc);
  load_set(L, R, cb0 + 3 * kstep, wbase, lo, A1, B1);
  mfma_set(A0, B0, acc);
  mfma_set(A1, B1, acc);

  // Store: lane holds D[m][n], m=w (row=hi*4+r), n=w' (col=lo); d = w - w'.
  const float s = 1.f / 128.f;
#pragma unroll
  for (int wt = 0; wt < 4; ++wt)
#pragma unroll
    for (int bt = 0; bt < 4; ++bt)
#pragma unroll
      for (int r = 0; r < 4; ++r) {
        const int w  = wbase + 16 * wt + hi * 4 + r;
        const int wp = wbase + 16 * (wt + bt) - 48 + lo;
        const int d  = w - wp;
        if (d >= 0 && d < Dn) {
          const float v = (wp >= 0) ? acc[wt][bt][r] * s : 0.f;
          out[((long long)b * Dn + d) * PL + (long long)h * Wn + w] = v;
        }
      }
}

extern "C" void kernel_launch(void* const* d_in, const int* in_sizes, int n_in,
                              void* d_out, int out_size, void* d_ws, size_t ws_size,
                              hipStream_t stream) {
  const float* Lf = (const float*)d_in[0];
  const float* Rf = (const float*)d_in[1];
  float* outp = (float*)d_out;
  costvol_kernel<<<dim3(960), dim3(256), 0, stream>>>(Lf, Rf, outp);
}

// Round 12
// 76.066 us; speedup vs baseline: 1.3718x; 1.3718x over previous
//
#include <hip/hip_runtime.h>

// Cost volume: out[b,d,h,w] = (1/C) * sum_c L[c,w] * R[c,w-d], zero for w<d.
// B=8, C=128, H=96, W=320, D=48, fp32 in/out.
//
// Round 12: MFMA banded-Gram (math verified r10/r11, absmax 2e-3) with the
// CORRECT delivery structure: coalesced global -> regs -> f16 LDS tiles ->
// ds_read fragments -> mfma. r10/r11 failed because hipcc won't keep
// direct-from-global per-lane frag loads in flight (VGPR 96/80, serial chains,
// nothing >8% busy). Streaming analysis: HBM 298MB ~= 47us floor; DS ~14K,
// MFMA ~5K cyc/CU -- all small. This should be HBM/streaming-bound.
//
// Block = one (b,h): 320 threads / 5 waves; wave ws owns w in [64ws, 64ws+64).
// Staging per 32-ch chunk: thread w=tid loads its w-column (32 scalar dwords,
// each wave-instruction = 64 consecutive w = 256B coalesced), packs f32->f16
// pairs, writes row Lt[w][0..31] / Rt[w][0..31] as 4x b128. Row stride 40 f16
// (80B): 16B aligned, non-power-of-2 bank pattern.
// Fragments: lane(lo,hi): A = Lt[wbase+16wt+lo][hi*8 +: 8] (one b128);
// B[i] = Rt[wbase-48+16i+lo][hi*8 +: 8], i=0..6 sliding window; same lane->k
// map both sides (permutation cancels, r10-verified); C/D: col=lane&15=w',
// row=(lane>>4)*4+reg=w [m89]. Band: bt window offsets {-48,-32,-16,0}.
// Boundary: clamp LDS row index >=0 (garbage), mask (wp>=0) at store.
// Barriers: 2/chunk; next-chunk global loads issued between them so the
// compute phase covers their latency; 3 blocks/CU (50KB LDS) for TLP.

typedef _Float16 half8 __attribute__((ext_vector_type(8)));
typedef float f32x4 __attribute__((ext_vector_type(4)));

constexpr int Cn = 128, Hn = 96, Wn = 320, Dn = 48;
constexpr long long PL = (long long)Hn * Wn;   // 30720
constexpr int CC = 32;                         // channels per chunk (K of one mfma)
constexpr int NCH = Cn / CC;                   // 4 chunks
constexpr int RS = 40;                         // f16 row stride (80 B)

__device__ __forceinline__ unsigned pack2f(float x, float y) {
  _Float16 a = (_Float16)x, b = (_Float16)y;
  unsigned short ua, ub;
  __builtin_memcpy(&ua, &a, 2);
  __builtin_memcpy(&ub, &b, 2);
  return (unsigned)ua | ((unsigned)ub << 16);
}

__global__ __launch_bounds__(320)
void costvol_kernel(const float* __restrict__ L, const float* __restrict__ R,
                    float* __restrict__ out) {
  __shared__ __align__(16) _Float16 Lt[Wn][RS];   // 25600 B
  __shared__ __align__(16) _Float16 Rt[Wn][RS];   // 25600 B

  const int bh = blockIdx.x;
  const int b = bh / Hn, h = bh % Hn;
  const int tid = threadIdx.x;
  const int w = tid;                         // this thread's staging row, 0..319
  const int wid = tid >> 6, lane = tid & 63;
  const int wbase = wid * 64;                // wave's 64-w span
  const int lo = lane & 15, hi = lane >> 4;

  const long long base = (long long)b * Cn * PL + (long long)h * Wn;
  const float* Lp = L + base + w;
  const float* Rp = R + base + w;

  f32x4 acc[4][4];
#pragma unroll
  for (int i = 0; i < 4; ++i)
#pragma unroll
    for (int j = 0; j < 4; ++j)
      acc[i][j] = f32x4{0.f, 0.f, 0.f, 0.f};

  float lv[CC], rv[CC];
  // ---- prologue: chunk 0 column loads (coalesced 256B/wave-instr) ----
#pragma unroll
  for (int cc = 0; cc < CC; ++cc) lv[cc] = Lp[(long long)cc * PL];
#pragma unroll
  for (int cc = 0; cc < CC; ++cc) rv[cc] = Rp[(long long)cc * PL];

  for (int t = 0; t < NCH; ++t) {
    // ---- pack f32->f16 pairs, write transposed rows (4x b128 each) ----
#pragma unroll
    for (int gq = 0; gq < 4; ++gq) {
      uint4 u;
      u.x = pack2f(lv[8 * gq + 0], lv[8 * gq + 1]);
      u.y = pack2f(lv[8 * gq + 2], lv[8 * gq + 3]);
      u.z = pack2f(lv[8 * gq + 4], lv[8 * gq + 5]);
      u.w = pack2f(lv[8 * gq + 6], lv[8 * gq + 7]);
      *(uint4*)&Lt[w][8 * gq] = u;
    }
#pragma unroll
    for (int gq = 0; gq < 4; ++gq) {
      uint4 u;
      u.x = pack2f(rv[8 * gq + 0], rv[8 * gq + 1]);
      u.y = pack2f(rv[8 * gq + 2], rv[8 * gq + 3]);
      u.z = pack2f(rv[8 * gq + 4], rv[8 * gq + 5]);
      u.w = pack2f(rv[8 * gq + 6], rv[8 * gq + 7]);
      *(uint4*)&Rt[w][8 * gq] = u;
    }
    __syncthreads();                         // tiles visible to all waves

    // ---- issue next chunk's loads; compute below hides their latency ----
    if (t + 1 < NCH) {
      const float* Lc = Lp + (long long)((t + 1) * CC) * PL;
      const float* Rc = Rp + (long long)((t + 1) * CC) * PL;
#pragma unroll
      for (int cc = 0; cc < CC; ++cc) lv[cc] = Lc[(long long)cc * PL];
#pragma unroll
      for (int cc = 0; cc < CC; ++cc) rv[cc] = Rc[(long long)cc * PL];
    }

    // ---- fragments from LDS + band MFMA (r10-verified mapping) ----
    half8 Bf[7];
#pragma unroll
    for (int i = 0; i < 7; ++i) {
      int wp = wbase - 48 + 16 * i + lo;
      wp = wp < 0 ? 0 : wp;                  // garbage row 0; masked at store
      Bf[i] = *(const half8*)&Rt[wp][hi * 8];
    }
#pragma unroll
    for (int wt = 0; wt < 4; ++wt) {
      const half8 Af = *(const half8*)&Lt[wbase + 16 * wt + lo][hi * 8];
#pragma unroll
      for (int bt = 0; bt < 4; ++bt)
        acc[wt][bt] = __builtin_amdgcn_mfma_f32_16x16x32_f16(
            Af, Bf[wt + bt], acc[wt][bt], 0, 0, 0);
    }
    __syncthreads();                         // reads done before next writes
  }

  // ---- store: lane holds D[m][n], m=w (row=hi*4+r), n=w' (col=lo); d=w-w' ----
  const float s = 1.f / 128.f;
#pragma unroll
  for (int wt = 0; wt < 4; ++wt)
#pragma unroll
    for (int bt = 0; bt < 4; ++bt)
#pragma unroll
      for (int r = 0; r < 4; ++r) {
        const int ww = wbase + 16 * wt + hi * 4 + r;
        const int wp = wbase + 16 * (wt + bt) - 48 + lo;
        const int d = ww - wp;
        if (d >= 0 && d < Dn) {
          const float v = (wp >= 0) ? acc[wt][bt][r] * s : 0.f;
          out[((long long)b * Dn + d) * PL + (long long)h * Wn + ww] = v;
        }
      }
}

extern "C" void kernel_launch(void* const* d_in, const int* in_sizes, int n_in,
                              void* d_out, int out_size, void* d_ws, size_t ws_size,
                              hipStream_t stream) {
  const float* Lf = (const float*)d_in[0];
  const float* Rf = (const float*)d_in[1];
  float* outp = (float*)d_out;
  costvol_kernel<<<dim3(8 * Hn), dim3(320), 0, stream>>>(Lf, Rf, outp);
}